// Round 2
// baseline (280.342 us; speedup 1.0000x reference)
//
#include <hip/hip_runtime.h>
#include <hip/hip_bf16.h>

typedef __bf16 bf16_t;
typedef bf16_t bf16x8 __attribute__((ext_vector_type(8)));
typedef float f32x4 __attribute__((ext_vector_type(4)));

constexpr int NB   = 16;
constexpr int NN   = 4096;
constexpr int PD   = 768;    // patch dim (K)
constexpr int HID  = 768;    // hidden (N out)
constexpr int PSZ  = 10240;  // pos table size
constexpr int MT   = NB * NN;       // 65536 rows
constexpr int BM   = 128;
constexpr int BN   = 128;
constexpr int BK   = 32;
constexpr int LDSS = 40;     // padded LDS row stride in bf16 elems (80 B)

__device__ __forceinline__ bf16x8 cvt8_affine(const float4& x, const float4& y,
                                              float s, float o) {
    bf16x8 r;
    r[0] = (bf16_t)__builtin_fmaf(s, x.x, o);
    r[1] = (bf16_t)__builtin_fmaf(s, x.y, o);
    r[2] = (bf16_t)__builtin_fmaf(s, x.z, o);
    r[3] = (bf16_t)__builtin_fmaf(s, x.w, o);
    r[4] = (bf16_t)__builtin_fmaf(s, y.x, o);
    r[5] = (bf16_t)__builtin_fmaf(s, y.y, o);
    r[6] = (bf16_t)__builtin_fmaf(s, y.z, o);
    r[7] = (bf16_t)__builtin_fmaf(s, y.w, o);
    return r;
}

__global__ __launch_bounds__(256)
void vpe_kernel(const float* __restrict__ pv,
                const int* __restrict__ posids,
                const int* __restrict__ mask,        // numpy bool -> int32 on device
                const float* __restrict__ W,
                const float* __restrict__ ptab,
                float* __restrict__ out)
{
    __shared__ alignas(16) bf16_t As[BM * LDSS];
    __shared__ alignas(16) bf16_t Bs[BN * LDSS];

    // XCD-aware swizzle: 3072 blocks, 3072 % 8 == 0 -> simple form bijective.
    const int nwg = gridDim.x;
    const int cpx = nwg >> 3;
    const int logical = (blockIdx.x & 7) * cpx + (blockIdx.x >> 3);
    const int mt = logical / 6;
    const int nt = logical - mt * 6;
    const int row0 = mt * BM;
    const int col0 = nt * BN;

    const int tid  = threadIdx.x;
    const int lane = tid & 63;
    const int wid  = tid >> 6;   // 4 waves
    const int wm   = wid >> 1;   // 0..1 (M)
    const int wn   = wid & 1;    // 0..1 (N)

    // staging: thread t loads 16 consecutive floats (half a 32-float row)
    const int srow = tid >> 1;          // 0..127
    const int scol = (tid & 1) << 4;    // 0 or 16

    const float* aptr = pv + (size_t)(row0 + srow) * PD + scol;
    const float* bptr = W  + (size_t)(col0 + srow) * PD + scol;
    bf16_t* a_lds_w = &As[srow * LDSS + scol];
    bf16_t* b_lds_w = &Bs[srow * LDSS + scol];

    f32x4 acc[4][4];
    #pragma unroll
    for (int i = 0; i < 4; ++i)
        #pragma unroll
        for (int j = 0; j < 4; ++j)
            acc[i][j] = f32x4{0.f, 0.f, 0.f, 0.f};

    const int lr = lane & 15;   // fragment row (A) / col (B) / col (D)
    const int kg = lane >> 4;   // k-group 0..3 (8 bf16 each)
    const bf16_t* a_rd = &As[(wm * 64 + lr) * LDSS + kg * 8];
    const bf16_t* b_rd = &Bs[(wn * 64 + lr) * LDSS + kg * 8];

    for (int k0 = 0; k0 < PD; k0 += BK) {
        float4 a0 = *(const float4*)(aptr + k0);
        float4 a1 = *(const float4*)(aptr + k0 + 4);
        float4 a2 = *(const float4*)(aptr + k0 + 8);
        float4 a3 = *(const float4*)(aptr + k0 + 12);
        float4 b0 = *(const float4*)(bptr + k0);
        float4 b1 = *(const float4*)(bptr + k0 + 4);
        float4 b2 = *(const float4*)(bptr + k0 + 8);
        float4 b3 = *(const float4*)(bptr + k0 + 12);

        // A: x = 2v - 1 (rescale to [-1,1]); B: plain convert
        bf16x8 av0 = cvt8_affine(a0, a1, 2.f, -1.f);
        bf16x8 av1 = cvt8_affine(a2, a3, 2.f, -1.f);
        bf16x8 bv0 = cvt8_affine(b0, b1, 1.f, 0.f);
        bf16x8 bv1 = cvt8_affine(b2, b3, 1.f, 0.f);

        __syncthreads();   // previous tile's reads complete
        *(bf16x8*)(a_lds_w)     = av0;
        *(bf16x8*)(a_lds_w + 8) = av1;
        *(bf16x8*)(b_lds_w)     = bv0;
        *(bf16x8*)(b_lds_w + 8) = bv1;
        __syncthreads();   // tile visible to all waves

        bf16x8 af[4], bfv[4];
        #pragma unroll
        for (int i = 0; i < 4; ++i) {
            af[i]  = *(const bf16x8*)(a_rd + i * 16 * LDSS);
            bfv[i] = *(const bf16x8*)(b_rd + i * 16 * LDSS);
        }
        #pragma unroll
        for (int i = 0; i < 4; ++i)
            #pragma unroll
            for (int j = 0; j < 4; ++j)
                acc[i][j] = __builtin_amdgcn_mfma_f32_16x16x32_bf16(
                    af[i], bfv[j], acc[i][j], 0, 0, 0);
    }

    // Epilogue: out = mask ? 0 : acc + ptab[0][p0][col] + ptab[1][p1][col]
    #pragma unroll
    for (int mi = 0; mi < 4; ++mi) {
        #pragma unroll
        for (int r = 0; r < 4; ++r) {
            const int grow = row0 + wm * 64 + mi * 16 + kg * 4 + r;
            const int mk = mask[grow];
            int p0 = posids[2 * grow];
            int p1 = posids[2 * grow + 1];
            p0 = p0 < 0 ? 0 : p0;
            p1 = p1 < 0 ? 0 : p1;
            const float* t0 = ptab + (size_t)p0 * HID;
            const float* t1 = ptab + (size_t)PSZ * HID + (size_t)p1 * HID;
            float* orow = out + (size_t)grow * HID;
            #pragma unroll
            for (int ni = 0; ni < 4; ++ni) {
                const int col = col0 + wn * 64 + ni * 16 + lr;
                const float v = acc[mi][ni][r] + t0[col] + t1[col];
                orow[col] = mk ? 0.f : v;
            }
        }
    }
}

extern "C" void kernel_launch(void* const* d_in, const int* in_sizes, int n_in,
                              void* d_out, int out_size, void* d_ws, size_t ws_size,
                              hipStream_t stream) {
    (void)in_sizes; (void)n_in; (void)d_ws; (void)ws_size; (void)out_size;
    const float* pv     = (const float*)d_in[0];
    const int*   posids = (const int*)d_in[1];
    const int*   mask   = (const int*)d_in[2];
    const float* W      = (const float*)d_in[3];
    const float* ptab   = (const float*)d_in[4];
    float*       out    = (float*)d_out;

    const int grid = (MT / BM) * (HID / BN);   // 512 * 6 = 3072
    hipLaunchKernelGGL(vpe_kernel, dim3(grid), dim3(256), 0, stream,
                       pv, posids, mask, W, ptab, out);
}

// Round 3
// 273.553 us; speedup vs baseline: 1.0248x; 1.0248x over previous
//
#include <hip/hip_runtime.h>
#include <hip/hip_bf16.h>

typedef __bf16 bf16_t;
typedef bf16_t bf16x8 __attribute__((ext_vector_type(8)));
typedef float f32x4 __attribute__((ext_vector_type(4)));

constexpr int NB   = 16;
constexpr int NN   = 4096;
constexpr int PD   = 768;    // patch dim (K)
constexpr int HID  = 768;    // hidden (N out)
constexpr int PSZ  = 10240;  // pos table size
constexpr int MT   = NB * NN;       // 65536 rows
constexpr int BM   = 128;
constexpr int BN   = 128;
constexpr int BK   = 32;
constexpr int LDSS = 40;     // padded LDS row stride in bf16 elems (80 B)
constexpr int NT   = PD / BK; // 24 k-tiles

__device__ __forceinline__ bf16x8 cvt8_affine(const float4& x, const float4& y,
                                              float s, float o) {
    bf16x8 r;
    r[0] = (bf16_t)__builtin_fmaf(s, x.x, o);
    r[1] = (bf16_t)__builtin_fmaf(s, x.y, o);
    r[2] = (bf16_t)__builtin_fmaf(s, x.z, o);
    r[3] = (bf16_t)__builtin_fmaf(s, x.w, o);
    r[4] = (bf16_t)__builtin_fmaf(s, y.x, o);
    r[5] = (bf16_t)__builtin_fmaf(s, y.y, o);
    r[6] = (bf16_t)__builtin_fmaf(s, y.z, o);
    r[7] = (bf16_t)__builtin_fmaf(s, y.w, o);
    return r;
}

__global__ __launch_bounds__(256, 2)
void vpe_kernel(const float* __restrict__ pv,
                const int* __restrict__ posids,
                const int* __restrict__ mask,        // numpy bool -> int32 on device
                const float* __restrict__ W,
                const float* __restrict__ ptab,
                float* __restrict__ out)
{
    __shared__ alignas(16) bf16_t As[2][BM * LDSS];
    __shared__ alignas(16) bf16_t Bs[2][BM * LDSS];

    // XCD-aware swizzle: 3072 blocks, 3072 % 8 == 0 -> simple form bijective.
    const int nwg = gridDim.x;
    const int cpx = nwg >> 3;
    const int logical = (blockIdx.x & 7) * cpx + (blockIdx.x >> 3);
    const int mt = logical / 6;
    const int nt = logical - mt * 6;
    const int row0 = mt * BM;
    const int col0 = nt * BN;

    const int tid  = threadIdx.x;
    const int lane = tid & 63;
    const int wid  = tid >> 6;   // 4 waves
    const int wm   = wid >> 1;   // 0..1 (M)
    const int wn   = wid & 1;    // 0..1 (N)

    // staging: thread t loads 16 consecutive floats (half a 32-float k-slice)
    const int srow = tid >> 1;          // 0..127
    const int scol = (tid & 1) << 4;    // 0 or 16

    const float* aptr = pv + (size_t)(row0 + srow) * PD + scol;
    const float* bptr = W  + (size_t)(col0 + srow) * PD + scol;
    const int lds_w_off = srow * LDSS + scol;

    f32x4 acc[4][4];
    #pragma unroll
    for (int i = 0; i < 4; ++i)
        #pragma unroll
        for (int j = 0; j < 4; ++j)
            acc[i][j] = f32x4{0.f, 0.f, 0.f, 0.f};

    const int lr = lane & 15;   // fragment row (A) / col (B) / col (D)
    const int kg = lane >> 4;   // k-group 0..3 (8 bf16 each)
    const int a_rd_off = (wm * 64 + lr) * LDSS + kg * 8;
    const int b_rd_off = (wn * 64 + lr) * LDSS + kg * 8;

    float4 ra[4], rb[4];

    // ---- prologue: stage tile 0 ----
    #pragma unroll
    for (int q = 0; q < 4; ++q) {
        ra[q] = *(const float4*)(aptr + q * 4);
        rb[q] = *(const float4*)(bptr + q * 4);
    }
    {
        bf16x8 av0 = cvt8_affine(ra[0], ra[1], 2.f, -1.f);
        bf16x8 av1 = cvt8_affine(ra[2], ra[3], 2.f, -1.f);
        bf16x8 bv0 = cvt8_affine(rb[0], rb[1], 1.f, 0.f);
        bf16x8 bv1 = cvt8_affine(rb[2], rb[3], 1.f, 0.f);
        *(bf16x8*)(&As[0][lds_w_off])     = av0;
        *(bf16x8*)(&As[0][lds_w_off] + 8) = av1;
        *(bf16x8*)(&Bs[0][lds_w_off])     = bv0;
        *(bf16x8*)(&Bs[0][lds_w_off] + 8) = bv1;
    }
    __syncthreads();

    int cur = 0;
    // ---- main loop: compute tile t from LDS, prefetch+stage tile t+1 ----
    for (int t = 0; t < NT - 1; ++t) {
        const int k1 = (t + 1) * BK;
        // 1. issue next tile's global loads (consumed after MFMA)
        #pragma unroll
        for (int q = 0; q < 4; ++q) {
            ra[q] = *(const float4*)(aptr + k1 + q * 4);
            rb[q] = *(const float4*)(bptr + k1 + q * 4);
        }

        // 2. fragments of current tile
        bf16x8 af[4], bfv[4];
        #pragma unroll
        for (int i = 0; i < 4; ++i) {
            af[i]  = *(const bf16x8*)(&As[cur][a_rd_off] + i * 16 * LDSS);
            bfv[i] = *(const bf16x8*)(&Bs[cur][b_rd_off] + i * 16 * LDSS);
        }

        // 3. MFMA
        #pragma unroll
        for (int i = 0; i < 4; ++i)
            #pragma unroll
            for (int j = 0; j < 4; ++j)
                acc[i][j] = __builtin_amdgcn_mfma_f32_16x16x32_bf16(
                    af[i], bfv[j], acc[i][j], 0, 0, 0);

        // 4. convert + stage next tile into the other buffer
        {
            bf16x8 av0 = cvt8_affine(ra[0], ra[1], 2.f, -1.f);
            bf16x8 av1 = cvt8_affine(ra[2], ra[3], 2.f, -1.f);
            bf16x8 bv0 = cvt8_affine(rb[0], rb[1], 1.f, 0.f);
            bf16x8 bv1 = cvt8_affine(rb[2], rb[3], 1.f, 0.f);
            const int nb = cur ^ 1;
            *(bf16x8*)(&As[nb][lds_w_off])     = av0;
            *(bf16x8*)(&As[nb][lds_w_off] + 8) = av1;
            *(bf16x8*)(&Bs[nb][lds_w_off])     = bv0;
            *(bf16x8*)(&Bs[nb][lds_w_off] + 8) = bv1;
        }
        __syncthreads();   // writes visible; all reads of buf[cur] drained
        cur ^= 1;
    }

    // ---- last tile ----
    {
        bf16x8 af[4], bfv[4];
        #pragma unroll
        for (int i = 0; i < 4; ++i) {
            af[i]  = *(const bf16x8*)(&As[cur][a_rd_off] + i * 16 * LDSS);
            bfv[i] = *(const bf16x8*)(&Bs[cur][b_rd_off] + i * 16 * LDSS);
        }
        #pragma unroll
        for (int i = 0; i < 4; ++i)
            #pragma unroll
            for (int j = 0; j < 4; ++j)
                acc[i][j] = __builtin_amdgcn_mfma_f32_16x16x32_bf16(
                    af[i], bfv[j], acc[i][j], 0, 0, 0);
    }

    // Epilogue: out = mask ? 0 : acc + ptab[0][p0][col] + ptab[1][p1][col]
    #pragma unroll
    for (int mi = 0; mi < 4; ++mi) {
        #pragma unroll
        for (int r = 0; r < 4; ++r) {
            const int grow = row0 + wm * 64 + mi * 16 + kg * 4 + r;
            const int mk = mask[grow];
            int p0 = posids[2 * grow];
            int p1 = posids[2 * grow + 1];
            p0 = p0 < 0 ? 0 : p0;
            p1 = p1 < 0 ? 0 : p1;
            const float* t0 = ptab + (size_t)p0 * HID;
            const float* t1 = ptab + (size_t)PSZ * HID + (size_t)p1 * HID;
            float* orow = out + (size_t)grow * HID;
            #pragma unroll
            for (int ni = 0; ni < 4; ++ni) {
                const int col = col0 + wn * 64 + ni * 16 + lr;
                const float v = acc[mi][ni][r] + t0[col] + t1[col];
                orow[col] = mk ? 0.f : v;
            }
        }
    }
}

extern "C" void kernel_launch(void* const* d_in, const int* in_sizes, int n_in,
                              void* d_out, int out_size, void* d_ws, size_t ws_size,
                              hipStream_t stream) {
    (void)in_sizes; (void)n_in; (void)d_ws; (void)ws_size; (void)out_size;
    const float* pv     = (const float*)d_in[0];
    const int*   posids = (const int*)d_in[1];
    const int*   mask   = (const int*)d_in[2];
    const float* W      = (const float*)d_in[3];
    const float* ptab   = (const float*)d_in[4];
    float*       out    = (float*)d_out;

    const int grid = (MT / BM) * (HID / BN);   // 512 * 6 = 3072
    hipLaunchKernelGGL(vpe_kernel, dim3(grid), dim3(256), 0, stream,
                       pv, posids, mask, W, ptab, out);
}

// Round 4
// 232.120 us; speedup vs baseline: 1.2077x; 1.1785x over previous
//
#include <hip/hip_runtime.h>
#include <hip/hip_bf16.h>

typedef __bf16 bf16_t;
typedef bf16_t bf16x8 __attribute__((ext_vector_type(8)));
typedef float f32x4 __attribute__((ext_vector_type(4)));

constexpr int NB   = 16;
constexpr int NN   = 4096;
constexpr int PD   = 768;    // patch dim (K)
constexpr int HID  = 768;    // hidden (N out)
constexpr int PSZ  = 10240;  // pos table size
constexpr int MT   = NB * NN;        // 65536 rows
constexpr int BM   = 128;
constexpr int BN   = 128;
constexpr int BK   = 32;
constexpr int NT   = PD / BK;        // 24 k-tiles
constexpr size_t PVN = (size_t)MT * PD;    // 50331648 floats
constexpr size_t WN  = (size_t)HID * PD;   // 589824 floats

__device__ __forceinline__ bf16x8 cvt8_affine(const float4& x, const float4& y,
                                              float s, float o) {
    bf16x8 r;
    r[0] = (bf16_t)__builtin_fmaf(s, x.x, o);
    r[1] = (bf16_t)__builtin_fmaf(s, x.y, o);
    r[2] = (bf16_t)__builtin_fmaf(s, x.z, o);
    r[3] = (bf16_t)__builtin_fmaf(s, x.w, o);
    r[4] = (bf16_t)__builtin_fmaf(s, y.x, o);
    r[5] = (bf16_t)__builtin_fmaf(s, y.y, o);
    r[6] = (bf16_t)__builtin_fmaf(s, y.z, o);
    r[7] = (bf16_t)__builtin_fmaf(s, y.w, o);
    return r;
}

// ---------------- Pass 1: fp32 -> bf16 convert (A gets 2v-1 fused) ----------
__global__ __launch_bounds__(256)
void cvt_kernel(const float* __restrict__ pv, const float* __restrict__ W,
                bf16_t* __restrict__ Ab, bf16_t* __restrict__ Wb)
{
    const size_t nunits = (PVN + WN) / 8;
    const size_t stride = (size_t)gridDim.x * blockDim.x;
    for (size_t u = (size_t)blockIdx.x * blockDim.x + threadIdx.x;
         u < nunits; u += stride) {
        if (u < PVN / 8) {
            const float4 x = ((const float4*)pv)[2 * u];
            const float4 y = ((const float4*)pv)[2 * u + 1];
            *(bf16x8*)(Ab + 8 * u) = cvt8_affine(x, y, 2.f, -1.f);
        } else {
            const size_t v = u - PVN / 8;
            const float4 x = ((const float4*)W)[2 * v];
            const float4 y = ((const float4*)W)[2 * v + 1];
            *(bf16x8*)(Wb + 8 * v) = cvt8_affine(x, y, 1.f, 0.f);
        }
    }
}

// ---------------- Pass 2: bf16 MFMA GEMM with global_load_lds ---------------
__device__ __forceinline__ void gload16(const void* g, void* l) {
    __builtin_amdgcn_global_load_lds(
        (const __attribute__((address_space(1))) void*)g,
        (__attribute__((address_space(3))) void*)l, 16, 0, 0);
}

__global__ __launch_bounds__(256, 2)
void gemm_kernel(const bf16_t* __restrict__ Ab,
                 const bf16_t* __restrict__ Wb,
                 const int* __restrict__ posids,
                 const int* __restrict__ mask,
                 const float* __restrict__ ptab,
                 float* __restrict__ out)
{
    __shared__ alignas(16) bf16_t As[2][BM * BK];   // linear: gload_lds needs it
    __shared__ alignas(16) bf16_t Bs[2][BN * BK];

    // XCD swizzle: 3072 % 8 == 0 -> simple form bijective.
    const int nwg = gridDim.x;
    const int cpx = nwg >> 3;
    const int logical = (blockIdx.x & 7) * cpx + (blockIdx.x >> 3);
    const int mt = logical / 6;
    const int nt = logical - mt * 6;
    const int row0 = mt * BM;
    const int col0 = nt * BN;

    const int tid  = threadIdx.x;
    const int lane = tid & 63;
    const int wid  = tid >> 6;
    const int wm   = wid >> 1;
    const int wn   = wid & 1;

    // staging: thread t owns a 16B slot; LDS byte = tid*16 (lane-linear in wave)
    const int srow = tid >> 2;          // 0..63
    const int sk   = (tid & 3) * 8;     // 0,8,16,24 (bf16 elems)
    const bf16_t* a0 = Ab + (size_t)(row0 + srow) * PD + sk;
    const bf16_t* b0 = Wb + (size_t)(col0 + srow) * PD + sk;
    const int lds_off_lo = srow * BK + sk;          // elems
    const int lds_off_hi = (srow + 64) * BK + sk;

    f32x4 acc[4][4];
    #pragma unroll
    for (int i = 0; i < 4; ++i)
        #pragma unroll
        for (int j = 0; j < 4; ++j)
            acc[i][j] = f32x4{0.f, 0.f, 0.f, 0.f};

    const int lr = lane & 15;
    const int kg = lane >> 4;
    const int a_rd_off = (wm * 64 + lr) * BK + kg * 8;
    const int b_rd_off = (wn * 64 + lr) * BK + kg * 8;

    // prologue: stage tile 0 into buf 0
    gload16(a0,           &As[0][lds_off_lo]);
    gload16(a0 + 64 * PD, &As[0][lds_off_hi]);
    gload16(b0,           &Bs[0][lds_off_lo]);
    gload16(b0 + 64 * PD, &Bs[0][lds_off_hi]);
    __syncthreads();   // compiler drains vmcnt before barrier

    int cur = 0;
    for (int t = 0; t < NT; ++t) {
        // issue next tile's staging first (in flight across ds_read+MFMA)
        if (t + 1 < NT) {
            const int k1 = (t + 1) * BK;
            const int nb = cur ^ 1;
            gload16(a0 + k1,           &As[nb][lds_off_lo]);
            gload16(a0 + 64 * PD + k1, &As[nb][lds_off_hi]);
            gload16(b0 + k1,           &Bs[nb][lds_off_lo]);
            gload16(b0 + 64 * PD + k1, &Bs[nb][lds_off_hi]);
        }

        bf16x8 af[4], bfv[4];
        #pragma unroll
        for (int i = 0; i < 4; ++i) {
            af[i]  = *(const bf16x8*)(&As[cur][a_rd_off + i * 16 * BK]);
            bfv[i] = *(const bf16x8*)(&Bs[cur][b_rd_off + i * 16 * BK]);
        }
        #pragma unroll
        for (int i = 0; i < 4; ++i)
            #pragma unroll
            for (int j = 0; j < 4; ++j)
                acc[i][j] = __builtin_amdgcn_mfma_f32_16x16x32_bf16(
                    af[i], bfv[j], acc[i][j], 0, 0, 0);

        __syncthreads();   // next-tile loads + all LDS ops drained; swap
        cur ^= 1;
    }

    // Epilogue: out = mask ? 0 : acc + ptab[0][p0][col] + ptab[1][p1][col]
    #pragma unroll
    for (int mi = 0; mi < 4; ++mi) {
        #pragma unroll
        for (int r = 0; r < 4; ++r) {
            const int grow = row0 + wm * 64 + mi * 16 + kg * 4 + r;
            const int mk = mask[grow];
            int p0 = posids[2 * grow];
            int p1 = posids[2 * grow + 1];
            p0 = p0 < 0 ? 0 : p0;
            p1 = p1 < 0 ? 0 : p1;
            const float* t0 = ptab + (size_t)p0 * HID;
            const float* t1 = ptab + (size_t)PSZ * HID + (size_t)p1 * HID;
            float* orow = out + (size_t)grow * HID;
            #pragma unroll
            for (int ni = 0; ni < 4; ++ni) {
                const int col = col0 + wn * 64 + ni * 16 + lr;
                const float v = acc[mi][ni][r] + t0[col] + t1[col];
                orow[col] = mk ? 0.f : v;
            }
        }
    }
}

// ---------------- Fallback (round-3 fused kernel, used if ws too small) -----
constexpr int LDSS = 40;

__global__ __launch_bounds__(256, 2)
void vpe_kernel(const float* __restrict__ pv,
                const int* __restrict__ posids,
                const int* __restrict__ mask,
                const float* __restrict__ W,
                const float* __restrict__ ptab,
                float* __restrict__ out)
{
    __shared__ alignas(16) bf16_t As[2][BM * LDSS];
    __shared__ alignas(16) bf16_t Bs[2][BM * LDSS];

    const int nwg = gridDim.x;
    const int cpx = nwg >> 3;
    const int logical = (blockIdx.x & 7) * cpx + (blockIdx.x >> 3);
    const int mt = logical / 6;
    const int nt = logical - mt * 6;
    const int row0 = mt * BM;
    const int col0 = nt * BN;

    const int tid  = threadIdx.x;
    const int lane = tid & 63;
    const int wid  = tid >> 6;
    const int wm   = wid >> 1;
    const int wn   = wid & 1;
    const int srow = tid >> 1;
    const int scol = (tid & 1) << 4;

    const float* aptr = pv + (size_t)(row0 + srow) * PD + scol;
    const float* bptr = W  + (size_t)(col0 + srow) * PD + scol;
    const int lds_w_off = srow * LDSS + scol;

    f32x4 acc[4][4];
    #pragma unroll
    for (int i = 0; i < 4; ++i)
        #pragma unroll
        for (int j = 0; j < 4; ++j)
            acc[i][j] = f32x4{0.f, 0.f, 0.f, 0.f};

    const int lr = lane & 15;
    const int kg = lane >> 4;
    const int a_rd_off = (wm * 64 + lr) * LDSS + kg * 8;
    const int b_rd_off = (wn * 64 + lr) * LDSS + kg * 8;

    float4 ra[4], rb[4];
    #pragma unroll
    for (int q = 0; q < 4; ++q) {
        ra[q] = *(const float4*)(aptr + q * 4);
        rb[q] = *(const float4*)(bptr + q * 4);
    }
    {
        bf16x8 av0 = cvt8_affine(ra[0], ra[1], 2.f, -1.f);
        bf16x8 av1 = cvt8_affine(ra[2], ra[3], 2.f, -1.f);
        bf16x8 bv0 = cvt8_affine(rb[0], rb[1], 1.f, 0.f);
        bf16x8 bv1 = cvt8_affine(rb[2], rb[3], 1.f, 0.f);
        *(bf16x8*)(&As[0][lds_w_off])     = av0;
        *(bf16x8*)(&As[0][lds_w_off] + 8) = av1;
        *(bf16x8*)(&Bs[0][lds_w_off])     = bv0;
        *(bf16x8*)(&Bs[0][lds_w_off] + 8) = bv1;
    }
    __syncthreads();

    int cur = 0;
    for (int t = 0; t < NT - 1; ++t) {
        const int k1 = (t + 1) * BK;
        #pragma unroll
        for (int q = 0; q < 4; ++q) {
            ra[q] = *(const float4*)(aptr + k1 + q * 4);
            rb[q] = *(const float4*)(bptr + k1 + q * 4);
        }
        bf16x8 af[4], bfv[4];
        #pragma unroll
        for (int i = 0; i < 4; ++i) {
            af[i]  = *(const bf16x8*)(&As[cur][a_rd_off] + i * 16 * LDSS);
            bfv[i] = *(const bf16x8*)(&Bs[cur][b_rd_off] + i * 16 * LDSS);
        }
        #pragma unroll
        for (int i = 0; i < 4; ++i)
            #pragma unroll
            for (int j = 0; j < 4; ++j)
                acc[i][j] = __builtin_amdgcn_mfma_f32_16x16x32_bf16(
                    af[i], bfv[j], acc[i][j], 0, 0, 0);
        {
            bf16x8 av0 = cvt8_affine(ra[0], ra[1], 2.f, -1.f);
            bf16x8 av1 = cvt8_affine(ra[2], ra[3], 2.f, -1.f);
            bf16x8 bv0 = cvt8_affine(rb[0], rb[1], 1.f, 0.f);
            bf16x8 bv1 = cvt8_affine(rb[2], rb[3], 1.f, 0.f);
            const int nb = cur ^ 1;
            *(bf16x8*)(&As[nb][lds_w_off])     = av0;
            *(bf16x8*)(&As[nb][lds_w_off] + 8) = av1;
            *(bf16x8*)(&Bs[nb][lds_w_off])     = bv0;
            *(bf16x8*)(&Bs[nb][lds_w_off] + 8) = bv1;
        }
        __syncthreads();
        cur ^= 1;
    }
    {
        bf16x8 af[4], bfv[4];
        #pragma unroll
        for (int i = 0; i < 4; ++i) {
            af[i]  = *(const bf16x8*)(&As[cur][a_rd_off] + i * 16 * LDSS);
            bfv[i] = *(const bf16x8*)(&Bs[cur][b_rd_off] + i * 16 * LDSS);
        }
        #pragma unroll
        for (int i = 0; i < 4; ++i)
            #pragma unroll
            for (int j = 0; j < 4; ++j)
                acc[i][j] = __builtin_amdgcn_mfma_f32_16x16x32_bf16(
                    af[i], bfv[j], acc[i][j], 0, 0, 0);
    }
    #pragma unroll
    for (int mi = 0; mi < 4; ++mi) {
        #pragma unroll
        for (int r = 0; r < 4; ++r) {
            const int grow = row0 + wm * 64 + mi * 16 + kg * 4 + r;
            const int mk = mask[grow];
            int p0 = posids[2 * grow];
            int p1 = posids[2 * grow + 1];
            p0 = p0 < 0 ? 0 : p0;
            p1 = p1 < 0 ? 0 : p1;
            const float* t0 = ptab + (size_t)p0 * HID;
            const float* t1 = ptab + (size_t)PSZ * HID + (size_t)p1 * HID;
            float* orow = out + (size_t)grow * HID;
            #pragma unroll
            for (int ni = 0; ni < 4; ++ni) {
                const int col = col0 + wn * 64 + ni * 16 + lr;
                const float v = acc[mi][ni][r] + t0[col] + t1[col];
                orow[col] = mk ? 0.f : v;
            }
        }
    }
}

extern "C" void kernel_launch(void* const* d_in, const int* in_sizes, int n_in,
                              void* d_out, int out_size, void* d_ws, size_t ws_size,
                              hipStream_t stream) {
    (void)in_sizes; (void)n_in; (void)out_size;
    const float* pv     = (const float*)d_in[0];
    const int*   posids = (const int*)d_in[1];
    const int*   mask   = (const int*)d_in[2];
    const float* W      = (const float*)d_in[3];
    const float* ptab   = (const float*)d_in[4];
    float*       out    = (float*)d_out;

    const size_t need = (PVN + WN) * sizeof(bf16_t);   // ~101.8 MB
    const int grid = (MT / BM) * (HID / BN);           // 3072

    if (ws_size >= need) {
        bf16_t* Ab = (bf16_t*)d_ws;
        bf16_t* Wb = Ab + PVN;
        hipLaunchKernelGGL(cvt_kernel, dim3(2048), dim3(256), 0, stream,
                           pv, W, Ab, Wb);
        hipLaunchKernelGGL(gemm_kernel, dim3(grid), dim3(256), 0, stream,
                           Ab, Wb, posids, mask, ptab, out);
    } else {
        hipLaunchKernelGGL(vpe_kernel, dim3(grid), dim3(256), 0, stream,
                           pv, posids, mask, W, ptab, out);
    }
}

// Round 5
// 211.852 us; speedup vs baseline: 1.3233x; 1.0957x over previous
//
#include <hip/hip_runtime.h>
#include <hip/hip_bf16.h>

typedef __bf16 bf16_t;
typedef bf16_t bf16x8 __attribute__((ext_vector_type(8)));
typedef float f32x4 __attribute__((ext_vector_type(4)));

constexpr int NB   = 16;
constexpr int NN   = 4096;
constexpr int PD   = 768;    // patch dim (K)
constexpr int HID  = 768;    // hidden (N out)
constexpr int PSZ  = 10240;  // pos table size
constexpr int MT   = NB * NN;        // 65536 rows
constexpr int BM   = 128;
constexpr int BN   = 128;
constexpr int BK   = 32;
constexpr int NT   = PD / BK;        // 24 k-tiles
constexpr int LDSC = 132;            // padded C-slice row stride (floats)
constexpr size_t PVN = (size_t)MT * PD;    // 50331648 floats
constexpr size_t WN  = (size_t)HID * PD;   // 589824 floats

__device__ __forceinline__ bf16x8 cvt8_affine(const float4& x, const float4& y,
                                              float s, float o) {
    bf16x8 r;
    r[0] = (bf16_t)__builtin_fmaf(s, x.x, o);
    r[1] = (bf16_t)__builtin_fmaf(s, x.y, o);
    r[2] = (bf16_t)__builtin_fmaf(s, x.z, o);
    r[3] = (bf16_t)__builtin_fmaf(s, x.w, o);
    r[4] = (bf16_t)__builtin_fmaf(s, y.x, o);
    r[5] = (bf16_t)__builtin_fmaf(s, y.y, o);
    r[6] = (bf16_t)__builtin_fmaf(s, y.z, o);
    r[7] = (bf16_t)__builtin_fmaf(s, y.w, o);
    return r;
}

// ---------------- Pass 1: fp32 -> bf16 convert (A gets 2v-1 fused) ----------
__global__ __launch_bounds__(256)
void cvt_kernel(const float* __restrict__ pv, const float* __restrict__ W,
                bf16_t* __restrict__ Ab, bf16_t* __restrict__ Wb)
{
    const size_t nunits = (PVN + WN) / 8;
    const size_t stride = (size_t)gridDim.x * blockDim.x;
    for (size_t u = (size_t)blockIdx.x * blockDim.x + threadIdx.x;
         u < nunits; u += stride) {
        if (u < PVN / 8) {
            const float4 x = ((const float4*)pv)[2 * u];
            const float4 y = ((const float4*)pv)[2 * u + 1];
            *(bf16x8*)(Ab + 8 * u) = cvt8_affine(x, y, 2.f, -1.f);
        } else {
            const size_t v = u - PVN / 8;
            const float4 x = ((const float4*)W)[2 * v];
            const float4 y = ((const float4*)W)[2 * v + 1];
            *(bf16x8*)(Wb + 8 * v) = cvt8_affine(x, y, 1.f, 0.f);
        }
    }
}

// ---------------- Pass 2: bf16 MFMA GEMM with global_load_lds ---------------
__device__ __forceinline__ void gload16(const void* g, void* l) {
    __builtin_amdgcn_global_load_lds(
        (const __attribute__((address_space(1))) void*)g,
        (__attribute__((address_space(3))) void*)l, 16, 0, 0);
}

__global__ __launch_bounds__(256, 2)
void gemm_kernel(const bf16_t* __restrict__ Ab,
                 const bf16_t* __restrict__ Wb,
                 const int* __restrict__ posids,
                 const int* __restrict__ mask,
                 const float* __restrict__ ptab,
                 float* __restrict__ out)
{
    // One buffer: A dbuf (16KB) + B dbuf (16KB); epilogue reuses it as
    // float Cs[32][LDSC] (16.9KB).
    __shared__ alignas(16) unsigned char smem[2 * BM * BK * 2 + 2 * BN * BK * 2];
    bf16_t* const Asb = (bf16_t*)smem;                 // [2][BM*BK]
    bf16_t* const Bsb = (bf16_t*)smem + 2 * BM * BK;   // [2][BN*BK]
    float*  const Cs  = (float*)smem;                  // [32][LDSC]

    // XCD swizzle: 3072 % 8 == 0 -> simple form bijective.
    const int nwg = gridDim.x;
    const int cpx = nwg >> 3;
    const int logical = (blockIdx.x & 7) * cpx + (blockIdx.x >> 3);
    const int mt = logical / 6;
    const int nt = logical - mt * 6;
    const int row0 = mt * BM;
    const int col0 = nt * BN;

    const int tid  = threadIdx.x;
    const int lane = tid & 63;
    const int wid  = tid >> 6;
    const int wm   = wid >> 1;
    const int wn   = wid & 1;

    // staging: thread t owns a 16B slot; LDS byte = tid*16 (lane-linear in wave)
    const int srow = tid >> 2;          // 0..63
    const int sk   = (tid & 3) * 8;     // 0,8,16,24 (bf16 elems)
    const bf16_t* a0 = Ab + (size_t)(row0 + srow) * PD + sk;
    const bf16_t* b0 = Wb + (size_t)(col0 + srow) * PD + sk;
    const int lds_off_lo = srow * BK + sk;          // elems
    const int lds_off_hi = (srow + 64) * BK + sk;

    f32x4 acc[4][4];
    #pragma unroll
    for (int i = 0; i < 4; ++i)
        #pragma unroll
        for (int j = 0; j < 4; ++j)
            acc[i][j] = f32x4{0.f, 0.f, 0.f, 0.f};

    const int lr = lane & 15;
    const int kg = lane >> 4;
    const int a_rd_off = (wm * 64 + lr) * BK + kg * 8;
    const int b_rd_off = (wn * 64 + lr) * BK + kg * 8;

    // prologue: stage tile 0 into buf 0
    gload16(a0,           Asb + lds_off_lo);
    gload16(a0 + 64 * PD, Asb + lds_off_hi);
    gload16(b0,           Bsb + lds_off_lo);
    gload16(b0 + 64 * PD, Bsb + lds_off_hi);
    __syncthreads();

    int cur = 0;
    for (int t = 0; t < NT; ++t) {
        if (t + 1 < NT) {
            const int k1 = (t + 1) * BK;
            const int nb = cur ^ 1;
            gload16(a0 + k1,           Asb + nb * (BM * BK) + lds_off_lo);
            gload16(a0 + 64 * PD + k1, Asb + nb * (BM * BK) + lds_off_hi);
            gload16(b0 + k1,           Bsb + nb * (BN * BK) + lds_off_lo);
            gload16(b0 + 64 * PD + k1, Bsb + nb * (BN * BK) + lds_off_hi);
        }

        bf16x8 af[4], bfv[4];
        #pragma unroll
        for (int i = 0; i < 4; ++i) {
            af[i]  = *(const bf16x8*)(Asb + cur * (BM * BK) + a_rd_off + i * 16 * BK);
            bfv[i] = *(const bf16x8*)(Bsb + cur * (BN * BK) + b_rd_off + i * 16 * BK);
        }
        #pragma unroll
        for (int i = 0; i < 4; ++i)
            #pragma unroll
            for (int j = 0; j < 4; ++j)
                acc[i][j] = __builtin_amdgcn_mfma_f32_16x16x32_bf16(
                    af[i], bfv[j], acc[i][j], 0, 0, 0);

        __syncthreads();
        cur ^= 1;
    }

    // ---- Epilogue: LDS-transposed, vectorized, mask-aware ----
    // Per mi: scatter 32x128 fp32 slice to LDS, then read back as float4 rows,
    // add pos-embedding gathers (float4), store float4.
    const int lrow_w  = wm * 16 + kg * 4;     // write: local row base (0..31)
    const int lcol_w  = wn * 64 + lr;         // write: local col base
    const int rr = tid >> 3;                  // read: local row 0..31
    const int cb = tid & 7;                   // read: col-group 0..7
    const int erow_local = (rr & 15) + (rr >> 4) * 64;

    #pragma unroll
    for (int mi = 0; mi < 4; ++mi) {
        if (mi) __syncthreads();              // prev slice's reads done
        #pragma unroll
        for (int r = 0; r < 4; ++r)
            #pragma unroll
            for (int ni = 0; ni < 4; ++ni)
                Cs[(lrow_w + r) * LDSC + lcol_w + ni * 16] = acc[mi][ni][r];
        __syncthreads();                      // slice visible

        const int grow = row0 + mi * 16 + erow_local;
        float* orow = out + (size_t)grow * HID + col0;
        const int mk = mask[grow];
        if (mk) {
            const float4 z{0.f, 0.f, 0.f, 0.f};
            #pragma unroll
            for (int j = 0; j < 4; ++j)
                *(float4*)(orow + (cb + 8 * j) * 4) = z;
        } else {
            int p0 = posids[2 * grow];
            int p1 = posids[2 * grow + 1];
            p0 = p0 < 0 ? 0 : p0;
            p1 = p1 < 0 ? 0 : p1;
            const float* t0 = ptab + (size_t)p0 * HID + col0;
            const float* t1 = ptab + (size_t)PSZ * HID + (size_t)p1 * HID + col0;
            #pragma unroll
            for (int j = 0; j < 4; ++j) {
                const int c = (cb + 8 * j) * 4;
                float4 v  = *(const float4*)&Cs[rr * LDSC + c];
                const float4 e0 = *(const float4*)(t0 + c);
                const float4 e1 = *(const float4*)(t1 + c);
                v.x += e0.x + e1.x;
                v.y += e0.y + e1.y;
                v.z += e0.z + e1.z;
                v.w += e0.w + e1.w;
                *(float4*)(orow + c) = v;
            }
        }
    }
}

// ---------------- Fallback (round-3 fused kernel, used if ws too small) -----
constexpr int LDSS = 40;

__global__ __launch_bounds__(256, 2)
void vpe_kernel(const float* __restrict__ pv,
                const int* __restrict__ posids,
                const int* __restrict__ mask,
                const float* __restrict__ W,
                const float* __restrict__ ptab,
                float* __restrict__ out)
{
    __shared__ alignas(16) bf16_t As[2][BM * LDSS];
    __shared__ alignas(16) bf16_t Bs[2][BM * LDSS];

    const int nwg = gridDim.x;
    const int cpx = nwg >> 3;
    const int logical = (blockIdx.x & 7) * cpx + (blockIdx.x >> 3);
    const int mt = logical / 6;
    const int nt = logical - mt * 6;
    const int row0 = mt * BM;
    const int col0 = nt * BN;

    const int tid  = threadIdx.x;
    const int lane = tid & 63;
    const int wid  = tid >> 6;
    const int wm   = wid >> 1;
    const int wn   = wid & 1;
    const int srow = tid >> 1;
    const int scol = (tid & 1) << 4;

    const float* aptr = pv + (size_t)(row0 + srow) * PD + scol;
    const float* bptr = W  + (size_t)(col0 + srow) * PD + scol;
    const int lds_w_off = srow * LDSS + scol;

    f32x4 acc[4][4];
    #pragma unroll
    for (int i = 0; i < 4; ++i)
        #pragma unroll
        for (int j = 0; j < 4; ++j)
            acc[i][j] = f32x4{0.f, 0.f, 0.f, 0.f};

    const int lr = lane & 15;
    const int kg = lane >> 4;
    const int a_rd_off = (wm * 64 + lr) * LDSS + kg * 8;
    const int b_rd_off = (wn * 64 + lr) * LDSS + kg * 8;

    float4 ra[4], rb[4];
    #pragma unroll
    for (int q = 0; q < 4; ++q) {
        ra[q] = *(const float4*)(aptr + q * 4);
        rb[q] = *(const float4*)(bptr + q * 4);
    }
    {
        bf16x8 av0 = cvt8_affine(ra[0], ra[1], 2.f, -1.f);
        bf16x8 av1 = cvt8_affine(ra[2], ra[3], 2.f, -1.f);
        bf16x8 bv0 = cvt8_affine(rb[0], rb[1], 1.f, 0.f);
        bf16x8 bv1 = cvt8_affine(rb[2], rb[3], 1.f, 0.f);
        *(bf16x8*)(&As[0][lds_w_off])     = av0;
        *(bf16x8*)(&As[0][lds_w_off] + 8) = av1;
        *(bf16x8*)(&Bs[0][lds_w_off])     = bv0;
        *(bf16x8*)(&Bs[0][lds_w_off] + 8) = bv1;
    }
    __syncthreads();

    int cur = 0;
    for (int t = 0; t < NT - 1; ++t) {
        const int k1 = (t + 1) * BK;
        #pragma unroll
        for (int q = 0; q < 4; ++q) {
            ra[q] = *(const float4*)(aptr + k1 + q * 4);
            rb[q] = *(const float4*)(bptr + k1 + q * 4);
        }
        bf16x8 af[4], bfv[4];
        #pragma unroll
        for (int i = 0; i < 4; ++i) {
            af[i]  = *(const bf16x8*)(&As[cur][a_rd_off] + i * 16 * LDSS);
            bfv[i] = *(const bf16x8*)(&Bs[cur][b_rd_off] + i * 16 * LDSS);
        }
        #pragma unroll
        for (int i = 0; i < 4; ++i)
            #pragma unroll
            for (int j = 0; j < 4; ++j)
                acc[i][j] = __builtin_amdgcn_mfma_f32_16x16x32_bf16(
                    af[i], bfv[j], acc[i][j], 0, 0, 0);
        {
            bf16x8 av0 = cvt8_affine(ra[0], ra[1], 2.f, -1.f);
            bf16x8 av1 = cvt8_affine(ra[2], ra[3], 2.f, -1.f);
            bf16x8 bv0 = cvt8_affine(rb[0], rb[1], 1.f, 0.f);
            bf16x8 bv1 = cvt8_affine(rb[2], rb[3], 1.f, 0.f);
            const int nb = cur ^ 1;
            *(bf16x8*)(&As[nb][lds_w_off])     = av0;
            *(bf16x8*)(&As[nb][lds_w_off] + 8) = av1;
            *(bf16x8*)(&Bs[nb][lds_w_off])     = bv0;
            *(bf16x8*)(&Bs[nb][lds_w_off] + 8) = bv1;
        }
        __syncthreads();
        cur ^= 1;
    }
    {
        bf16x8 af[4], bfv[4];
        #pragma unroll
        for (int i = 0; i < 4; ++i) {
            af[i]  = *(const bf16x8*)(&As[cur][a_rd_off] + i * 16 * LDSS);
            bfv[i] = *(const bf16x8*)(&Bs[cur][b_rd_off] + i * 16 * LDSS);
        }
        #pragma unroll
        for (int i = 0; i < 4; ++i)
            #pragma unroll
            for (int j = 0; j < 4; ++j)
                acc[i][j] = __builtin_amdgcn_mfma_f32_16x16x32_bf16(
                    af[i], bfv[j], acc[i][j], 0, 0, 0);
    }
    #pragma unroll
    for (int mi = 0; mi < 4; ++mi) {
        #pragma unroll
        for (int r = 0; r < 4; ++r) {
            const int grow = row0 + wm * 64 + mi * 16 + kg * 4 + r;
            const int mk = mask[grow];
            int p0 = posids[2 * grow];
            int p1 = posids[2 * grow + 1];
            p0 = p0 < 0 ? 0 : p0;
            p1 = p1 < 0 ? 0 : p1;
            const float* t0 = ptab + (size_t)p0 * HID;
            const float* t1 = ptab + (size_t)PSZ * HID + (size_t)p1 * HID;
            float* orow = out + (size_t)grow * HID;
            #pragma unroll
            for (int ni = 0; ni < 4; ++ni) {
                const int col = col0 + wn * 64 + ni * 16 + lr;
                const float v = acc[mi][ni][r] + t0[col] + t1[col];
                orow[col] = mk ? 0.f : v;
            }
        }
    }
}

extern "C" void kernel_launch(void* const* d_in, const int* in_sizes, int n_in,
                              void* d_out, int out_size, void* d_ws, size_t ws_size,
                              hipStream_t stream) {
    (void)in_sizes; (void)n_in; (void)out_size;
    const float* pv     = (const float*)d_in[0];
    const int*   posids = (const int*)d_in[1];
    const int*   mask   = (const int*)d_in[2];
    const float* W      = (const float*)d_in[3];
    const float* ptab   = (const float*)d_in[4];
    float*       out    = (float*)d_out;

    const size_t need = (PVN + WN) * sizeof(bf16_t);   // ~101.8 MB
    const int grid = (MT / BM) * (HID / BN);           // 3072

    if (ws_size >= need) {
        bf16_t* Ab = (bf16_t*)d_ws;
        bf16_t* Wb = Ab + PVN;
        hipLaunchKernelGGL(cvt_kernel, dim3(2048), dim3(256), 0, stream,
                           pv, W, Ab, Wb);
        hipLaunchKernelGGL(gemm_kernel, dim3(grid), dim3(256), 0, stream,
                           Ab, Wb, posids, mask, ptab, out);
    } else {
        hipLaunchKernelGGL(vpe_kernel, dim3(grid), dim3(256), 0, stream,
                           pv, posids, mask, W, ptab, out);
    }
}